// Round 14
// baseline (288.226 us; speedup 1.0000x reference)
//
#include <hip/hip_runtime.h>
#include <hip/hip_bf16.h>

#define B_ 2
#define C_ 256
#define N_ 110592
#define CN_ ((size_t)C_ * N_)
#define NCK_ 128          // K-chunks in gram (grid 256)
#define T_ 27             // 32-col tiles per chunk: 128*27*32 = 110592

typedef __attribute__((ext_vector_type(4))) float f32x4;
typedef __attribute__((ext_vector_type(8))) short bf16x8;
typedef __attribute__((ext_vector_type(4))) short bf16x4;

__device__ __forceinline__ short f2bf(float f) {
    union { float f; unsigned u; } v; v.f = f;
    unsigned r = (v.u + 0x7fffu + ((v.u >> 16) & 1u)) >> 16;
    return (short)(r & 0xffffu);
}

__device__ __forceinline__ void gload16f(const float* g, float* l) {
    __builtin_amdgcn_global_load_lds(
        (const __attribute__((address_space(1))) void*)g,
        (__attribute__((address_space(3))) void*)l, 16, 0, 0);
}

__device__ __forceinline__ void gload16s(const short* g, short* l) {
    __builtin_amdgcn_global_load_lds(
        (const __attribute__((address_space(1))) void*)g,
        (__attribute__((address_space(3))) void*)l, 16, 0, 0);
}

// ---------------- k_prep: x(f32) -> xg + xf + rowsum partials -------------
// grid (72, 4, B), 256 thr. Block = 64 rows x 1536 cols, 6 slabs of 256.
// R14 FIX: staging loop must cover ALL 4096 16B-slots of the 64KB tile
// (16 slots/thread, slot = r*256 + t). R11-R13 covered only 1024 slots
// (rows 0-3,16-19,32-35,48-51) leaving 48/64 rows stale -> absmax ~120.
__global__ __launch_bounds__(256) void k_prep(
        const float* __restrict__ x, short* __restrict__ xg,
        short* __restrict__ xf, float* __restrict__ rs2) {
    __shared__ float Xs[64 * 256];      // 64 KB, linear (DMA dest)
    __shared__ float rsum_s[64];
    const int t = threadIdx.x;
    const int nb = blockIdx.x, q = blockIdx.y, b = blockIdx.z;
    const int c0 = q * 64, n0 = nb * 1536;
    const float* xb = x + (size_t)b * CN_;
    short* xgb = xg + (size_t)b * CN_;
    short* xfb = xf + (size_t)b * CN_;
    const int rr = t >> 2, qq = t & 3;
    const int kgl = t >> 5, nl = t & 31;
    float racc = 0.f;

    for (int sl = 0; sl < 6; ++sl) {
        // DMA stage: 16 x 16B per thread (4096 slots total); each wave's
        // 64 lanes cover one row's 1-KB contiguous segment.
#pragma unroll
        for (int r = 0; r < 16; ++r) {
            int slot = r * 256 + t;
            int row = slot >> 6, c4 = slot & 63;
            gload16f(xb + (size_t)(c0 + row) * N_ + n0 + sl * 256 + c4 * 4,
                     Xs + slot * 4);
        }
        __syncthreads();        // full drain (vmcnt0) -> tile visible
        // rowsum (row rr, quarter qq)
        {
            const f32x4* src = (const f32x4*)(Xs + rr * 256 + qq * 64);
#pragma unroll
            for (int j = 0; j < 16; ++j) {
                f32x4 v = src[j];
                racc += (v.x + v.y) + (v.z + v.w);
            }
        }
        // xg emit: 8 tiles of 32 cols; dest granule qq holds src granule qq^(rr&3)
#pragma unroll
        for (int tau = 0; tau < 8; ++tau) {
            int gl = qq ^ (rr & 3);
            const float* s2 = Xs + rr * 256 + tau * 32 + gl * 8;
            bf16x8 h;
#pragma unroll
            for (int e = 0; e < 8; ++e) h[e] = f2bf(s2[e]);
            size_t tg = (size_t)(nb * 48 + sl * 8 + tau);
            *(bf16x8*)(xgb + tg * 8192 + (c0 + rr) * 32 + qq * 8) = h;
        }
        // xf emit: ch-packed
#pragma unroll
        for (int nn = 0; nn < 8; ++nn) {
            bf16x8 h;
#pragma unroll
            for (int j = 0; j < 8; ++j)
                h[j] = f2bf(Xs[(kgl * 8 + j) * 256 + nn * 32 + nl]);
            *(bf16x8*)(xfb + ((size_t)(q * 8 + kgl) * N_ +
                              n0 + sl * 256 + nn * 32 + nl) * 8) = h;
        }
        __syncthreads();
    }
    // combine rowsum quarters (lanes t^1, t^2 share rr)
    racc += __shfl_xor(racc, 1);
    racc += __shfl_xor(racc, 2);
    if ((t & 3) == 0) rsum_s[t >> 2] = racc;
    __syncthreads();
    if (t < 64)
        rs2[((size_t)b * C_ + c0 + t) * 72 + nb] = rsum_s[t];
}

// ---------------- k_gram_bf: Gram from xg (bf16, swizzled tiles) ----------
// 1024 thr / 16 waves, grid (128, B) = 256 blocks. Per tile: ONE contiguous
// 16-KB DMA; counted vmcnt(1) steady / vmcnt(0) final tile; iteration ends
// with lgkmcnt(0)+sched_barrier(0) so no outstanding ds_read crosses the
// barrier that releases its buffer for DMA reuse.
__global__ __launch_bounds__(1024, 4) void k_gram_bf(
        const short* __restrict__ xg, float* __restrict__ part) {
    __shared__ short Xs[3 * 8192];      // 3 x 16 KB
    const int t = threadIdx.x, lane = t & 63, wave = t >> 6;
    const int chunk = blockIdx.x, b = blockIdx.y;
    const int cw0 = (wave & 3) * 64, dw0 = (wave >> 2) * 64;
    const int r16 = lane & 15, g16 = lane >> 4;
    const int gsw = g16 ^ (r16 & 3);    // swizzled granule (same all frag rows)
    const short* xgb = xg + (size_t)b * CN_ + (size_t)chunk * T_ * 8192;

    f32x4 acc[4][4];
#pragma unroll
    for (int i = 0; i < 4; ++i)
#pragma unroll
        for (int j = 0; j < 4; ++j) acc[i][j] = f32x4{0.f, 0.f, 0.f, 0.f};

#define GST(TT, BB) gload16s(xgb + (size_t)(TT) * 8192 + t * 8, Xs + (BB) * 8192 + t * 8);

    GST(0, 0)
    GST(1, 1)

    int bb = 0;
    for (int tt = 0; tt < T_; ++tt) {
        if (tt + 1 < T_) asm volatile("s_waitcnt vmcnt(1)" ::: "memory");
        else             asm volatile("s_waitcnt vmcnt(0)" ::: "memory");
        __builtin_amdgcn_sched_barrier(0);
        __builtin_amdgcn_s_barrier();
        if (tt + 2 < T_) {
            int bn = bb + 2; if (bn >= 3) bn -= 3;
            GST(tt + 2, bn)
        }
        const short* base = Xs + bb * 8192;
        bf16x8 afr[4];
#pragma unroll
        for (int ct = 0; ct < 4; ++ct)
            afr[ct] = *(const bf16x8*)(base + (cw0 + ct * 16 + r16) * 32 + gsw * 8);
#pragma unroll
        for (int dt = 0; dt < 4; ++dt) {
            bf16x8 bfr = *(const bf16x8*)(base + (dw0 + dt * 16 + r16) * 32 + gsw * 8);
#pragma unroll
            for (int ct = 0; ct < 4; ++ct)
                acc[ct][dt] = __builtin_amdgcn_mfma_f32_16x16x32_bf16(
                    afr[ct], bfr, acc[ct][dt], 0, 0, 0);
        }
        // drain ALL LDS reads before the next barrier releases this buffer
        asm volatile("s_waitcnt lgkmcnt(0)" ::: "memory");
        __builtin_amdgcn_sched_barrier(0);
        ++bb; if (bb >= 3) bb -= 3;
    }
#undef GST

    float* pp = part + ((size_t)b * NCK_ + chunk) * (C_ * C_);
#pragma unroll
    for (int ct = 0; ct < 4; ++ct)
#pragma unroll
        for (int dt = 0; dt < 4; ++dt) {
            int d = dw0 + dt * 16 + r16;
#pragma unroll
            for (int rr = 0; rr < 4; ++rr) {
                int c = cw0 + ct * 16 + g16 * 4 + rr;
                pp[(size_t)c * C_ + d] = acc[ct][dt][rr];
            }
        }
}

// ------------- k_reduce2: vectorized reduce + stats (big path) ------------
__global__ void k_reduce2(const float* __restrict__ part, const float* __restrict__ rs2,
                          float* __restrict__ Graw, float* __restrict__ mean,
                          float* __restrict__ rsig) {
    __shared__ f32x4 red[4 * 64];
    __shared__ float rsr[72];
    __shared__ float diag_s;
    int bid = blockIdx.x;
    int b = bid >> 8, c = bid & 255;
    int t = threadIdx.x;
    int dq = t & 63, ps = t >> 6;
    f32x4 s = f32x4{0.f, 0.f, 0.f, 0.f};
    for (int p = ps; p < NCK_; p += 4)
        s += *(const f32x4*)(part + (((size_t)b * NCK_ + p) * (C_ * C_)) +
                             (size_t)c * C_ + dq * 4);
    red[ps * 64 + dq] = s;
    if (t < 72) rsr[t] = rs2[((size_t)b * C_ + c) * 72 + t];
    __syncthreads();
    if (t < 64) {
        f32x4 a = red[t] + red[64 + t] + red[128 + t] + red[192 + t];
        *(f32x4*)(Graw + ((size_t)b * C_ + c) * C_ + t * 4) = a;
        if (t == (c >> 2)) {
            int m3 = c & 3;
            diag_s = (m3 == 0) ? a.x : ((m3 == 1) ? a.y : ((m3 == 2) ? a.z : a.w));
        }
    }
    __syncthreads();
    if (t == 0) {
        float tot = 0.f;
#pragma unroll
        for (int i = 0; i < 72; ++i) tot += rsr[i];
        float m = tot / (float)N_;
        float var = diag_s / (float)N_ - m * m;
        mean[b * C_ + c] = m;
        rsig[b * C_ + c] = rsqrtf(var + 1e-5f);
    }
}

// ======== FALLBACK PATH (small ws) — R10 verbatim (proven) ========
__global__ __launch_bounds__(1024, 4) void k_gram_fb(
        const float* __restrict__ x, float* __restrict__ part,
        float* __restrict__ rspart) {
    __shared__ float Xf[3 * 8192];
    __shared__ short Xb[256 * 40];
    __shared__ float rs_s[256];
    const int t = threadIdx.x, lane = t & 63, wave = t >> 6;
    const int chunk = blockIdx.x, b = blockIdx.y;
    const int k0 = chunk * (T_ * 32);
    const int cw0 = (wave & 3) * 64, dw0 = (wave >> 2) * 64;
    const int r16 = lane & 15, g16 = lane >> 4;
    const float* xb = x + (size_t)b * CN_;
    const int s_row = t >> 3;
    const int g_src = (t & 7) ^ (s_row & 7);
    const int rp_r = t >> 2, rp_q = t & 3;
    const int rp_g0 = (2 * rp_q) ^ (rp_r & 7);

    f32x4 acc[4][4];
#pragma unroll
    for (int i = 0; i < 4; ++i)
#pragma unroll
        for (int j = 0; j < 4; ++j) acc[i][j] = f32x4{0.f, 0.f, 0.f, 0.f};
    float rs = 0.f;

#define GSTAGE(TT, BB)                                                        \
    {                                                                         \
        const float* gsrc = xb + k0 + (TT) * 32 + g_src * 4;                  \
        float* ldst = Xf + (BB) * 8192;                                       \
        gload16f(gsrc + (size_t)s_row * N_, ldst + t * 4);                    \
        gload16f(gsrc + (size_t)(s_row + 128) * N_, ldst + (t + 1024) * 4);   \
    }
    GSTAGE(0, 0)
    GSTAGE(1, 1)
    int bb = 0;
    for (int tt = 0; tt < T_; ++tt) {
        if (tt + 1 < T_) asm volatile("s_waitcnt vmcnt(2)" ::: "memory");
        else             asm volatile("s_waitcnt vmcnt(0)" ::: "memory");
        __builtin_amdgcn_s_barrier();
        if (tt + 2 < T_) {
            int bn = bb + 2; if (bn >= 3) bn -= 3;
            GSTAGE(tt + 2, bn)
        }
        {
            const float* src = Xf + bb * 8192 + rp_r * 32;
            f32x4 a = *(const f32x4*)(src + rp_g0 * 4);
            f32x4 c = *(const f32x4*)(src + (rp_g0 ^ 1) * 4);
            rs += ((a.x + a.y) + (a.z + a.w)) + ((c.x + c.y) + (c.z + c.w));
            bf16x8 h;
            h[0] = f2bf(a.x); h[1] = f2bf(a.y); h[2] = f2bf(a.z); h[3] = f2bf(a.w);
            h[4] = f2bf(c.x); h[5] = f2bf(c.y); h[6] = f2bf(c.z); h[7] = f2bf(c.w);
            *(bf16x8*)(Xb + rp_r * 40 + rp_q * 8) = h;
        }
        asm volatile("s_waitcnt lgkmcnt(0)" ::: "memory");
        __builtin_amdgcn_s_barrier();
        {
            bf16x8 afr[4];
#pragma unroll
            for (int ct = 0; ct < 4; ++ct)
                afr[ct] = *(const bf16x8*)(Xb + (cw0 + ct * 16 + r16) * 40 + g16 * 8);
#pragma unroll
            for (int dt = 0; dt < 4; ++dt) {
                bf16x8 bfr = *(const bf16x8*)(Xb + (dw0 + dt * 16 + r16) * 40 + g16 * 8);
#pragma unroll
                for (int ct = 0; ct < 4; ++ct)
                    acc[ct][dt] = __builtin_amdgcn_mfma_f32_16x16x32_bf16(
                        afr[ct], bfr, acc[ct][dt], 0, 0, 0);
            }
        }
        ++bb; if (bb >= 3) bb -= 3;
    }
#undef GSTAGE
    rs += __shfl_xor(rs, 1);
    rs += __shfl_xor(rs, 2);
    if (rp_q == 0) rs_s[rp_r] = rs;
    __syncthreads();
    if (t < 256) rspart[((size_t)b * NCK_ + chunk) * C_ + t] = rs_s[t];
    float* pp = part + ((size_t)b * NCK_ + chunk) * (C_ * C_);
#pragma unroll
    for (int ct = 0; ct < 4; ++ct)
#pragma unroll
        for (int dt = 0; dt < 4; ++dt) {
            int d = dw0 + dt * 16 + r16;
#pragma unroll
            for (int rr = 0; rr < 4; ++rr) {
                int c = cw0 + ct * 16 + g16 * 4 + rr;
                pp[(size_t)c * C_ + d] = acc[ct][dt][rr];
            }
        }
}

__global__ void k_reduce_fb(const float* __restrict__ part, const float* __restrict__ rspart,
                            float* __restrict__ Graw, float* __restrict__ mean,
                            float* __restrict__ rsig) {
    __shared__ float diag_s;
    __shared__ float red[256];
    int bid = blockIdx.x;
    int b = bid >> 8, c = bid & 255;
    int d = threadIdx.x;
    float s = 0.f;
    for (int p = 0; p < NCK_; ++p)
        s += part[(((size_t)b * NCK_ + p) * (C_ * C_)) + (size_t)c * C_ + d];
    Graw[((size_t)b * C_ + c) * C_ + d] = s;
    if (d == c) diag_s = s;
    float rsum = 0.f;
    for (int p = d; p < NCK_; p += 256)
        rsum += rspart[((size_t)b * NCK_ + p) * C_ + c];
    red[d] = rsum;
    __syncthreads();
    if (d < 128) red[d] += red[d + 128];
    __syncthreads();
    if (d < 64) red[d] += red[d + 64];
    __syncthreads();
    if (d == 0) {
        float tot = 0.f;
#pragma unroll
        for (int i = 0; i < 64; ++i) tot += red[i];
        float m = tot / (float)N_;
        float var = diag_s / (float)N_ - m * m;
        mean[b * C_ + c] = m;
        rsig[b * C_ + c] = rsqrtf(var + 1e-5f);
    }
}

// ---------------- P = Wq * Gn ----------------
__global__ void k_gemm1(const float* __restrict__ Wq, const float* __restrict__ Graw,
                        const float* __restrict__ mean, const float* __restrict__ rsig,
                        float* __restrict__ P) {
    int bid = blockIdx.x; int b = bid >> 8, c = bid & 255; int d = threadIdx.x;
    const float* G = Graw + (size_t)b * C_ * C_;
    const float* mb = mean + b * C_;
    const float* rb = rsig + b * C_;
    float md = mb[d], rd = rb[d];
    float a1 = 0.f, a2 = 0.f;
    for (int e = 0; e < C_; ++e) {
        float w = Wq[(size_t)c * C_ + e] * rb[e];
        a1 += w * G[(size_t)e * C_ + d];
        a2 += w * mb[e];
    }
    P[((size_t)b * C_ + c) * C_ + d] = rd * a1 - (float)N_ * md * rd * a2;
}

// ---------------- atten = softmax(P*Wk^T + N bq bk^T)/16 + outer/16 ------
__global__ void k_attn(const float* __restrict__ P, const float* __restrict__ Wk,
                       const float* __restrict__ bq, const float* __restrict__ bk,
                       const float* __restrict__ outer, float* __restrict__ atten) {
    __shared__ float Pr_s[256];
    __shared__ float red[8];
    int bid = blockIdx.x; int b = bid >> 8, c = bid & 255; int d = threadIdx.x;
    int lane = d & 63, w = d >> 6;
    Pr_s[d] = P[((size_t)b * C_ + c) * C_ + d];
    __syncthreads();
    float a = 0.f;
#pragma unroll 4
    for (int e4 = 0; e4 < 64; ++e4) {
        f32x4 wv = *(const f32x4*)(Wk + (size_t)d * C_ + e4 * 4);
        f32x4 pv = *(const f32x4*)(Pr_s + e4 * 4);
        a += wv.x * pv.x + wv.y * pv.y + wv.z * pv.z + wv.w * pv.w;
    }
    float v = a + (float)N_ * bq[c] * bk[d];
    float m = v;
    for (int off = 32; off; off >>= 1) m = fmaxf(m, __shfl_xor(m, off));
    if (lane == 0) red[w] = m;
    __syncthreads();
    m = fmaxf(fmaxf(red[0], red[1]), fmaxf(red[2], red[3]));
    float e = __expf(v - m);
    float s = e;
    for (int off = 32; off; off >>= 1) s += __shfl_xor(s, off);
    if (lane == 0) red[4 + w] = s;
    __syncthreads();
    s = red[4] + red[5] + red[6] + red[7];
    atten[((size_t)b * C_ + c) * C_ + d] = e / (s * 16.f) + outer[(size_t)c * C_ + d] * 0.0625f;
}

// ------------- A = (atten*Wv + I)*diag(rsig) in FRAGMENT layout, beta ----
__global__ void k_gemm3(const float* __restrict__ atten, const float* __restrict__ Wv,
                        const float* __restrict__ bv, const float* __restrict__ mean,
                        const float* __restrict__ rsig, short* __restrict__ Abf,
                        float* __restrict__ beta) {
    __shared__ float red[4];
    int bid = blockIdx.x; int b = bid >> 8, c = bid & 255; int g = threadIdx.x;
    int lane = g & 63, w = g >> 6;
    const float* at = atten + ((size_t)b * C_ + c) * C_;
    float a = 0.f;
    for (int d = 0; d < C_; ++d)
        a += at[d] * Wv[(size_t)d * C_ + g];
    float Ag = (a + ((g == c) ? 1.f : 0.f)) * rsig[b * C_ + g];
    Abf[(size_t)b * C_ * C_ + ((size_t)(g >> 3) * C_ + c) * 8 + (g & 7)] = f2bf(Ag);
    float u = at[g] * bv[g] - Ag * mean[b * C_ + g];
    for (int off = 32; off; off >>= 1) u += __shfl_xor(u, off);
    if (lane == 0) red[w] = u;
    __syncthreads();
    if (g == 0) beta[b * C_ + c] = red[0] + red[1] + red[2] + red[3];
}

// ------------- Pass 2: out = A*x + beta (R8/R10 known-good) ---------------
__global__ __launch_bounds__(512, 4) void k_out2(
        const short* __restrict__ xf, const short* __restrict__ Abf,
        const float* __restrict__ beta, float* __restrict__ out) {
    __shared__ short Xt[2 * 8192];
    __shared__ float Wb[8 * 32 * 33];
    const int t = threadIdx.x, lane = t & 63, wave = t >> 6;
    const int nb = blockIdx.x, b = blockIdx.y;
    const int col = lane & 15, g16 = lane >> 4;
    const int cw0 = wave * 32;
    const int r8 = lane >> 3, s8 = lane & 7;
    const int n_blk = nb * 256;
    const short* Ab = Abf + (size_t)b * C_ * C_;
    const short* xfb = xf + (size_t)b * CN_;
    float* ob = out + (size_t)b * CN_;
    float* wl = Wb + wave * (32 * 33);

    bf16x8 Af[2][8];
#pragma unroll
    for (int ct = 0; ct < 2; ++ct)
#pragma unroll
        for (int ks = 0; ks < 8; ++ks)
            Af[ct][ks] = *(const bf16x8*)(Ab +
                ((size_t)((ks * 4 + g16) * 256 + cw0 + ct * 16 + col)) * 8);
    float bet[4];
#pragma unroll
    for (int j = 0; j < 4; ++j) bet[j] = beta[b * C_ + cw0 + j * 8 + r8];

#define STAGE(BUF, N0)                                                        \
    {                                                                         \
        _Pragma("unroll")                                                     \
        for (int r = 0; r < 2; ++r) {                                         \
            int s = r * 512 + t;                                              \
            int kg = s >> 5, nsl = s & 31;                                    \
            int nn = nsl ^ (kg & 3);                                          \
            gload16s(xfb + ((size_t)kg * N_ + (N0) + nn) * 8,                 \
                     Xt + (BUF) * 8192 + s * 8);                              \
        }                                                                     \
    }

    STAGE(0, n_blk)
    __syncthreads();

    for (int it = 0; it < 8; ++it) {
        const int cur = it & 1;
        if (it + 1 < 8) STAGE(cur ^ 1, n_blk + (it + 1) * 32)
        const int n0 = n_blk + it * 32;

        f32x4 acc[2][2];
#pragma unroll
        for (int i = 0; i < 2; ++i) {
            acc[i][0] = f32x4{0.f, 0.f, 0.f, 0.f};
            acc[i][1] = f32x4{0.f, 0.f, 0.f, 0.f};
        }
#pragma unroll
        for (int ks = 0; ks < 8; ++ks) {
            const int kg = ks * 4 + g16;
            bf16x8 x0 = *(const bf16x8*)(Xt + cur * 8192 +
                                         (kg * 32 + (col ^ (kg & 3))) * 8);
            bf16x8 x1 = *(const bf16x8*)(Xt + cur * 8192 +
                                         (kg * 32 + ((16 + col) ^ (kg & 3))) * 8);
            acc[0][0] = __builtin_amdgcn_mfma_f32_16x16x32_bf16(Af[0][ks], x0, acc[0][0], 0, 0, 0);
            acc[1][0] = __builtin_amdgcn_mfma_f32_16x16x32_bf16(Af[1][ks], x0, acc[1][0], 0, 0, 0);
            acc[0][1] = __builtin_amdgcn_mfma_f32_16x16x32_bf16(Af[0][ks], x1, acc[0][1], 0, 0, 0);
            acc[1][1] = __builtin_amdgcn_mfma_f32_16x16x32_bf16(Af[1][ks], x1, acc[1][1], 0, 0, 0);
        }
#pragma unroll
        for (int ct = 0; ct < 2; ++ct)
#pragma unroll
            for (int nt = 0; nt < 2; ++nt)
#pragma unroll
                for (int rr = 0; rr < 4; ++rr)
                    wl[(ct * 16 + g16 * 4 + rr) * 33 + nt * 16 + col] = acc[ct][nt][rr];
#pragma unroll
        for (int j = 0; j < 4; ++j) {
            f32x4 v = *(const f32x4*)(wl + (j * 8 + r8) * 33 + s8 * 4);
            float bb = bet[j];
            v.x += bb; v.y += bb; v.z += bb; v.w += bb;
            *(f32x4*)(ob + (size_t)(cw0 + j * 8 + r8) * N_ + n0 + s8 * 4) = v;
        }
        __syncthreads();
    }
#undef STAGE
}

// ------------- Pass 2 (fallback, small ws): gathers f32 x ----------------
__global__ __launch_bounds__(512) void k_out_f32(
        const float* __restrict__ x, const short* __restrict__ Abf,
        const float* __restrict__ beta, float* __restrict__ out) {
    __shared__ float beta_s[256];
    const int t = threadIdx.x, lane = t & 63, wave = t >> 6;
    const int nb = blockIdx.x, b = blockIdx.y;
    const int col = lane & 15, g16 = lane >> 4;
    const int n_w = nb * 256 + wave * 32;
    if (t < 256) beta_s[t] = beta[b * C_ + t];
    __syncthreads();
    const short* Ab = Abf + (size_t)b * C_ * C_;
    const float* xb = x + (size_t)b * CN_;
    float* ob = out + (size_t)b * CN_;

    f32x4 acc[16][2];
#pragma unroll
    for (int i = 0; i < 16; ++i) {
        acc[i][0] = f32x4{0.f, 0.f, 0.f, 0.f};
        acc[i][1] = f32x4{0.f, 0.f, 0.f, 0.f};
    }
    float pf[2][16];
#define XL(KS, NT, J) xb[(size_t)((KS)*32 + g16 * 8 + (J)) * N_ + n_w + (NT)*16 + col]
#pragma unroll
    for (int j = 0; j < 8; ++j) { pf[0][j] = XL(0, 0, j); pf[0][8 + j] = XL(0, 1, j); }
#pragma unroll
    for (int ks = 0; ks < 8; ++ks) {
        if (ks + 1 < 8) {
#pragma unroll
            for (int j = 0; j < 8; ++j) {
                pf[(ks + 1) & 1][j] = XL(ks + 1, 0, j);
                pf[(ks + 1) & 1][8 + j] = XL(ks + 1, 1, j);
            }
        }
        bf16x8 xa, xv;
#pragma unroll
        for (int j = 0; j < 8; ++j) {
            xa[j] = f2bf(pf[ks & 1][j]);
            xv[j] = f2bf(pf[ks & 1][8 + j]);
        }
#pragma unroll
        for (int ct = 0; ct < 16; ++ct) {
            bf16x8 afr = *(const bf16x8*)(Ab + ((size_t)((ks * 4 + g16) * 256 + ct * 16 + col)) * 8);
            acc[ct][0] = __builtin_amdgcn_mfma_f32_16x16x32_bf16(afr, xa, acc[ct][0], 0, 0, 0);
            acc[ct][1] = __builtin_amdgcn_mfma_f32_16x16x32_bf16(afr, xv, acc[ct][1], 0, 0, 0);
        }
    }
#undef XL
#pragma unroll
    for (int ct = 0; ct < 16; ++ct)
#pragma unroll
        for (int nt = 0; nt < 2; ++nt) {
            int n = n_w + nt * 16 + col;
#pragma unroll
            for (int rr = 0; rr < 4; ++rr) {
                int c = ct * 16 + g16 * 4 + rr;
                ob[(size_t)c * N_ + n] = acc[ct][nt][rr] + beta_s[c];
            }
        }
}

extern "C" void kernel_launch(void* const* d_in, const int* in_sizes, int n_in,
                              void* d_out, int out_size, void* d_ws, size_t ws_size,
                              hipStream_t stream) {
    (void)in_sizes; (void)n_in; (void)out_size;
    const float* x     = (const float*)d_in[0];
    const float* Wq    = (const float*)d_in[1];
    const float* bq    = (const float*)d_in[2];
    const float* Wk    = (const float*)d_in[3];
    const float* bk    = (const float*)d_in[4];
    const float* Wv    = (const float*)d_in[5];
    const float* bv    = (const float*)d_in[6];
    const float* outer = (const float*)d_in[7];
    float* out = (float*)d_out;

    char* w = (char*)d_ws;
    float* mean   = (float*)(w + 0);
    float* rsig   = (float*)(w + 2048);
    float* beta   = (float*)(w + 4096);
    float* rs2    = (float*)(w + 8192);   // big: 2*256*72*4 = 147456
    float* rspart = (float*)(w + 8192);   // fb : 128*2*256*4 = 262144
    float* Graw   = (float*)(w + 270336);
    float* P      = (float*)(w + 794624);
    float* atten  = (float*)(w + 1318912);
    short* Abf    = (short*)(w + 1843200);
    const size_t fixed = 2105344;
    const size_t part_bytes = (size_t)NCK_ * B_ * C_ * C_ * 4;   // 67.1 MB
    const size_t xf_bytes = (size_t)B_ * CN_ * 2;                // 113.25 MB
    const size_t xg_bytes = (size_t)B_ * CN_ * 2;                // 113.25 MB
    float* part = (float*)(w + fixed);
    short* xf   = (short*)(w + fixed + part_bytes);
    short* xg   = (short*)(w + fixed + part_bytes + xf_bytes);

    const bool big = ws_size >= fixed + part_bytes + xf_bytes + xg_bytes;

    if (big) {
        k_prep   <<<dim3(72, 4, B_), 256, 0, stream>>>(x, xg, xf, rs2);
        k_gram_bf<<<dim3(NCK_, B_), 1024, 0, stream>>>(xg, part);
        k_reduce2<<<dim3(B_ * C_), 256, 0, stream>>>(part, rs2, Graw, mean, rsig);
    } else {
        k_gram_fb  <<<dim3(NCK_, B_), 1024, 0, stream>>>(x, part, rspart);
        k_reduce_fb<<<dim3(B_ * C_), 256, 0, stream>>>(part, rspart, Graw, mean, rsig);
    }
    k_gemm1 <<<dim3(B_ * C_), C_, 0, stream>>>(Wq, Graw, mean, rsig, P);
    k_attn  <<<dim3(B_ * C_), C_, 0, stream>>>(P, Wk, bq, bk, outer, atten);
    k_gemm3 <<<dim3(B_ * C_), C_, 0, stream>>>(atten, Wv, bv, mean, rsig, Abf, beta);
    if (big) {
        k_out2  <<<dim3(N_ / 256, B_), 512, 0, stream>>>(xf, Abf, beta, out);
    } else {
        k_out_f32<<<dim3(N_ / 256, B_), 512, 0, stream>>>(x, Abf, beta, out);
    }
}

// Round 15
// 279.728 us; speedup vs baseline: 1.0304x; 1.0304x over previous
//
#include <hip/hip_runtime.h>
#include <hip/hip_bf16.h>

#define B_ 2
#define C_ 256
#define N_ 110592
#define CN_ ((size_t)C_ * N_)
#define NCK_ 128          // K-chunks in gram (grid 256)
#define T_ 27             // 32-col tiles per chunk: 128*27*32 = 110592
#define NB_ 144           // prep n-blocks (768 n each)

typedef __attribute__((ext_vector_type(4))) float f32x4;
typedef __attribute__((ext_vector_type(8))) short bf16x8;
typedef __attribute__((ext_vector_type(4))) short bf16x4;

__device__ __forceinline__ short f2bf(float f) {
    union { float f; unsigned u; } v; v.f = f;
    unsigned r = (v.u + 0x7fffu + ((v.u >> 16) & 1u)) >> 16;
    return (short)(r & 0xffffu);
}

__device__ __forceinline__ void gload16f(const float* g, float* l) {
    __builtin_amdgcn_global_load_lds(
        (const __attribute__((address_space(1))) void*)g,
        (__attribute__((address_space(3))) void*)l, 16, 0, 0);
}

__device__ __forceinline__ void gload16s(const short* g, short* l) {
    __builtin_amdgcn_global_load_lds(
        (const __attribute__((address_space(1))) void*)g,
        (__attribute__((address_space(3))) void*)l, 16, 0, 0);
}

// ---------------- k_prep: x(f32) -> xg + xf + rowsum partials -------------
// R15 rewrite: no f32 LDS tile. Threads read x to REGISTERS (1-KB coalesced
// segments), convert once; xg + rowsum handled entirely in registers (xg is
// same orientation as x); only xf's 8-ch transpose goes through a bf16 LDS
// tile (pitch 272 shorts -> ~2-way banks). 35 KB LDS, grid 1152 -> 4 blk/CU.
__global__ __launch_bounds__(256) void k_prep(
        const float* __restrict__ x, short* __restrict__ xg,
        short* __restrict__ xf, float* __restrict__ rs2) {
    __shared__ short Xs16[64 * 272];    // 34.8 KB bf16, pitch 272 shorts
    const int t = threadIdx.x;
    const int nb = blockIdx.x, q = blockIdx.y, b = blockIdx.z;
    const int c0 = q * 64, n0 = nb * 768;
    const float* xb = x + (size_t)b * CN_;
    short* xgb = xg + (size_t)b * CN_;
    short* xfb = xf + (size_t)b * CN_;
    const int lg = t >> 5;              // row group 0..7
    const int ln = t & 31;              // n granule (8 floats)
    float racc[8] = {0.f, 0.f, 0.f, 0.f, 0.f, 0.f, 0.f, 0.f};

    for (int sl = 0; sl < 3; ++sl) {
        const int ns = n0 + sl * 256;
        // read -> convert -> {xg global, Xs16 LDS}, rowsum in regs
#pragma unroll
        for (int i = 0; i < 8; ++i) {
            const int rl = i * 8 + lg;
            const int c = c0 + rl;
            const float* src = xb + (size_t)c * N_ + ns + ln * 8;
            f32x4 v0 = *(const f32x4*)(src);
            f32x4 v1 = *(const f32x4*)(src + 4);
            racc[i] += ((v0.x + v0.y) + (v0.z + v0.w)) +
                       ((v1.x + v1.y) + (v1.z + v1.w));
            bf16x8 h;
            h[0] = f2bf(v0.x); h[1] = f2bf(v0.y); h[2] = f2bf(v0.z); h[3] = f2bf(v0.w);
            h[4] = f2bf(v1.x); h[5] = f2bf(v1.y); h[6] = f2bf(v1.z); h[7] = f2bf(v1.w);
            *(bf16x8*)(Xs16 + rl * 272 + ln * 8) = h;
            const int tg = nb * 24 + sl * 8 + (ln >> 2);
            const int gd = (ln & 3) ^ (c & 3);
            *(bf16x8*)(xgb + (size_t)tg * 8192 + c * 32 + gd * 8) = h;
        }
        __syncthreads();
        // xf gather: 8 channels per word (kgl = t>>5 is the local k-group)
#pragma unroll
        for (int nn = 0; nn < 8; ++nn) {
            bf16x8 h;
#pragma unroll
            for (int j = 0; j < 8; ++j)
                h[j] = Xs16[(lg * 8 + j) * 272 + nn * 32 + ln];
            *(bf16x8*)(xfb + ((size_t)(q * 8 + lg) * N_ + ns + nn * 32 + ln) * 8) = h;
        }
        __syncthreads();
    }
    // rowsums: 32 lanes (ln) share row i*8+lg
#pragma unroll
    for (int i = 0; i < 8; ++i) {
        float r = racc[i];
        r += __shfl_xor(r, 1);
        r += __shfl_xor(r, 2);
        r += __shfl_xor(r, 4);
        r += __shfl_xor(r, 8);
        r += __shfl_xor(r, 16);
        if (ln == 0)
            rs2[((size_t)b * C_ + c0 + i * 8 + lg) * NB_ + nb] = r;
    }
}

// ---------------- k_gram_bf: Gram from xg (bf16, swizzled tiles) ----------
// (R14 verbatim — passed.) 1024 thr, grid (128, B). One contiguous 16-KB DMA
// per tile; vmcnt(1) steady / vmcnt(0) final; lgkmcnt(0)+sched_barrier ends
// each iteration so no ds_read outlives its buffer.
__global__ __launch_bounds__(1024, 4) void k_gram_bf(
        const short* __restrict__ xg, float* __restrict__ part) {
    __shared__ short Xs[3 * 8192];      // 3 x 16 KB
    const int t = threadIdx.x, lane = t & 63, wave = t >> 6;
    const int chunk = blockIdx.x, b = blockIdx.y;
    const int cw0 = (wave & 3) * 64, dw0 = (wave >> 2) * 64;
    const int r16 = lane & 15, g16 = lane >> 4;
    const int gsw = g16 ^ (r16 & 3);
    const short* xgb = xg + (size_t)b * CN_ + (size_t)chunk * T_ * 8192;

    f32x4 acc[4][4];
#pragma unroll
    for (int i = 0; i < 4; ++i)
#pragma unroll
        for (int j = 0; j < 4; ++j) acc[i][j] = f32x4{0.f, 0.f, 0.f, 0.f};

#define GST(TT, BB) gload16s(xgb + (size_t)(TT) * 8192 + t * 8, Xs + (BB) * 8192 + t * 8);

    GST(0, 0)
    GST(1, 1)

    int bb = 0;
    for (int tt = 0; tt < T_; ++tt) {
        if (tt + 1 < T_) asm volatile("s_waitcnt vmcnt(1)" ::: "memory");
        else             asm volatile("s_waitcnt vmcnt(0)" ::: "memory");
        __builtin_amdgcn_sched_barrier(0);
        __builtin_amdgcn_s_barrier();
        if (tt + 2 < T_) {
            int bn = bb + 2; if (bn >= 3) bn -= 3;
            GST(tt + 2, bn)
        }
        const short* base = Xs + bb * 8192;
        bf16x8 afr[4];
#pragma unroll
        for (int ct = 0; ct < 4; ++ct)
            afr[ct] = *(const bf16x8*)(base + (cw0 + ct * 16 + r16) * 32 + gsw * 8);
#pragma unroll
        for (int dt = 0; dt < 4; ++dt) {
            bf16x8 bfr = *(const bf16x8*)(base + (dw0 + dt * 16 + r16) * 32 + gsw * 8);
#pragma unroll
            for (int ct = 0; ct < 4; ++ct)
                acc[ct][dt] = __builtin_amdgcn_mfma_f32_16x16x32_bf16(
                    afr[ct], bfr, acc[ct][dt], 0, 0, 0);
        }
        asm volatile("s_waitcnt lgkmcnt(0)" ::: "memory");
        __builtin_amdgcn_sched_barrier(0);
        ++bb; if (bb >= 3) bb -= 3;
    }
#undef GST

    float* pp = part + ((size_t)b * NCK_ + chunk) * (C_ * C_);
#pragma unroll
    for (int ct = 0; ct < 4; ++ct)
#pragma unroll
        for (int dt = 0; dt < 4; ++dt) {
            int d = dw0 + dt * 16 + r16;
#pragma unroll
            for (int rr = 0; rr < 4; ++rr) {
                int c = cw0 + ct * 16 + g16 * 4 + rr;
                pp[(size_t)c * C_ + d] = acc[ct][dt][rr];
            }
        }
}

// ------------- k_reduce2: vectorized reduce + stats (big path) ------------
__global__ void k_reduce2(const float* __restrict__ part, const float* __restrict__ rs2,
                          float* __restrict__ Graw, float* __restrict__ mean,
                          float* __restrict__ rsig) {
    __shared__ f32x4 red[4 * 64];
    __shared__ float rsr[NB_];
    __shared__ float diag_s;
    int bid = blockIdx.x;
    int b = bid >> 8, c = bid & 255;
    int t = threadIdx.x;
    int dq = t & 63, ps = t >> 6;
    f32x4 s = f32x4{0.f, 0.f, 0.f, 0.f};
    for (int p = ps; p < NCK_; p += 4)
        s += *(const f32x4*)(part + (((size_t)b * NCK_ + p) * (C_ * C_)) +
                             (size_t)c * C_ + dq * 4);
    red[ps * 64 + dq] = s;
    if (t < NB_) rsr[t] = rs2[((size_t)b * C_ + c) * NB_ + t];
    __syncthreads();
    if (t < 64) {
        f32x4 a = red[t] + red[64 + t] + red[128 + t] + red[192 + t];
        *(f32x4*)(Graw + ((size_t)b * C_ + c) * C_ + t * 4) = a;
        if (t == (c >> 2)) {
            int m3 = c & 3;
            diag_s = (m3 == 0) ? a.x : ((m3 == 1) ? a.y : ((m3 == 2) ? a.z : a.w));
        }
    }
    __syncthreads();
    if (t == 0) {
        float tot = 0.f;
#pragma unroll
        for (int i = 0; i < NB_; ++i) tot += rsr[i];
        float m = tot / (float)N_;
        float var = diag_s / (float)N_ - m * m;
        mean[b * C_ + c] = m;
        rsig[b * C_ + c] = rsqrtf(var + 1e-5f);
    }
}

// ======== FALLBACK PATH (small ws) — R10 verbatim (proven) ========
__global__ __launch_bounds__(1024, 4) void k_gram_fb(
        const float* __restrict__ x, float* __restrict__ part,
        float* __restrict__ rspart) {
    __shared__ float Xf[3 * 8192];
    __shared__ short Xb[256 * 40];
    __shared__ float rs_s[256];
    const int t = threadIdx.x, lane = t & 63, wave = t >> 6;
    const int chunk = blockIdx.x, b = blockIdx.y;
    const int k0 = chunk * (T_ * 32);
    const int cw0 = (wave & 3) * 64, dw0 = (wave >> 2) * 64;
    const int r16 = lane & 15, g16 = lane >> 4;
    const float* xb = x + (size_t)b * CN_;
    const int s_row = t >> 3;
    const int g_src = (t & 7) ^ (s_row & 7);
    const int rp_r = t >> 2, rp_q = t & 3;
    const int rp_g0 = (2 * rp_q) ^ (rp_r & 7);

    f32x4 acc[4][4];
#pragma unroll
    for (int i = 0; i < 4; ++i)
#pragma unroll
        for (int j = 0; j < 4; ++j) acc[i][j] = f32x4{0.f, 0.f, 0.f, 0.f};
    float rs = 0.f;

#define GSTAGE(TT, BB)                                                        \
    {                                                                         \
        const float* gsrc = xb + k0 + (TT) * 32 + g_src * 4;                  \
        float* ldst = Xf + (BB) * 8192;                                       \
        gload16f(gsrc + (size_t)s_row * N_, ldst + t * 4);                    \
        gload16f(gsrc + (size_t)(s_row + 128) * N_, ldst + (t + 1024) * 4);   \
    }
    GSTAGE(0, 0)
    GSTAGE(1, 1)
    int bb = 0;
    for (int tt = 0; tt < T_; ++tt) {
        if (tt + 1 < T_) asm volatile("s_waitcnt vmcnt(2)" ::: "memory");
        else             asm volatile("s_waitcnt vmcnt(0)" ::: "memory");
        __builtin_amdgcn_s_barrier();
        if (tt + 2 < T_) {
            int bn = bb + 2; if (bn >= 3) bn -= 3;
            GSTAGE(tt + 2, bn)
        }
        {
            const float* src = Xf + bb * 8192 + rp_r * 32;
            f32x4 a = *(const f32x4*)(src + rp_g0 * 4);
            f32x4 c = *(const f32x4*)(src + (rp_g0 ^ 1) * 4);
            rs += ((a.x + a.y) + (a.z + a.w)) + ((c.x + c.y) + (c.z + c.w));
            bf16x8 h;
            h[0] = f2bf(a.x); h[1] = f2bf(a.y); h[2] = f2bf(a.z); h[3] = f2bf(a.w);
            h[4] = f2bf(c.x); h[5] = f2bf(c.y); h[6] = f2bf(c.z); h[7] = f2bf(c.w);
            *(bf16x8*)(Xb + rp_r * 40 + rp_q * 8) = h;
        }
        asm volatile("s_waitcnt lgkmcnt(0)" ::: "memory");
        __builtin_amdgcn_s_barrier();
        {
            bf16x8 afr[4];
#pragma unroll
            for (int ct = 0; ct < 4; ++ct)
                afr[ct] = *(const bf16x8*)(Xb + (cw0 + ct * 16 + r16) * 40 + g16 * 8);
#pragma unroll
            for (int dt = 0; dt < 4; ++dt) {
                bf16x8 bfr = *(const bf16x8*)(Xb + (dw0 + dt * 16 + r16) * 40 + g16 * 8);
#pragma unroll
                for (int ct = 0; ct < 4; ++ct)
                    acc[ct][dt] = __builtin_amdgcn_mfma_f32_16x16x32_bf16(
                        afr[ct], bfr, acc[ct][dt], 0, 0, 0);
            }
        }
        ++bb; if (bb >= 3) bb -= 3;
    }
#undef GSTAGE
    rs += __shfl_xor(rs, 1);
    rs += __shfl_xor(rs, 2);
    if (rp_q == 0) rs_s[rp_r] = rs;
    __syncthreads();
    if (t < 256) rspart[((size_t)b * NCK_ + chunk) * C_ + t] = rs_s[t];
    float* pp = part + ((size_t)b * NCK_ + chunk) * (C_ * C_);
#pragma unroll
    for (int ct = 0; ct < 4; ++ct)
#pragma unroll
        for (int dt = 0; dt < 4; ++dt) {
            int d = dw0 + dt * 16 + r16;
#pragma unroll
            for (int rr = 0; rr < 4; ++rr) {
                int c = cw0 + ct * 16 + g16 * 4 + rr;
                pp[(size_t)c * C_ + d] = acc[ct][dt][rr];
            }
        }
}

__global__ void k_reduce_fb(const float* __restrict__ part, const float* __restrict__ rspart,
                            float* __restrict__ Graw, float* __restrict__ mean,
                            float* __restrict__ rsig) {
    __shared__ float diag_s;
    __shared__ float red[256];
    int bid = blockIdx.x;
    int b = bid >> 8, c = bid & 255;
    int d = threadIdx.x;
    float s = 0.f;
    for (int p = 0; p < NCK_; ++p)
        s += part[(((size_t)b * NCK_ + p) * (C_ * C_)) + (size_t)c * C_ + d];
    Graw[((size_t)b * C_ + c) * C_ + d] = s;
    if (d == c) diag_s = s;
    float rsum = 0.f;
    for (int p = d; p < NCK_; p += 256)
        rsum += rspart[((size_t)b * NCK_ + p) * C_ + c];
    red[d] = rsum;
    __syncthreads();
    if (d < 128) red[d] += red[d + 128];
    __syncthreads();
    if (d < 64) red[d] += red[d + 64];
    __syncthreads();
    if (d == 0) {
        float tot = 0.f;
#pragma unroll
        for (int i = 0; i < 64; ++i) tot += red[i];
        float m = tot / (float)N_;
        float var = diag_s / (float)N_ - m * m;
        mean[b * C_ + c] = m;
        rsig[b * C_ + c] = rsqrtf(var + 1e-5f);
    }
}

// ---------------- P = Wq * Gn ----------------
__global__ void k_gemm1(const float* __restrict__ Wq, const float* __restrict__ Graw,
                        const float* __restrict__ mean, const float* __restrict__ rsig,
                        float* __restrict__ P) {
    int bid = blockIdx.x; int b = bid >> 8, c = bid & 255; int d = threadIdx.x;
    const float* G = Graw + (size_t)b * C_ * C_;
    const float* mb = mean + b * C_;
    const float* rb = rsig + b * C_;
    float md = mb[d], rd = rb[d];
    float a1 = 0.f, a2 = 0.f;
    for (int e = 0; e < C_; ++e) {
        float w = Wq[(size_t)c * C_ + e] * rb[e];
        a1 += w * G[(size_t)e * C_ + d];
        a2 += w * mb[e];
    }
    P[((size_t)b * C_ + c) * C_ + d] = rd * a1 - (float)N_ * md * rd * a2;
}

// ---------------- atten = softmax(P*Wk^T + N bq bk^T)/16 + outer/16 ------
__global__ void k_attn(const float* __restrict__ P, const float* __restrict__ Wk,
                       const float* __restrict__ bq, const float* __restrict__ bk,
                       const float* __restrict__ outer, float* __restrict__ atten) {
    __shared__ float Pr_s[256];
    __shared__ float red[8];
    int bid = blockIdx.x; int b = bid >> 8, c = bid & 255; int d = threadIdx.x;
    int lane = d & 63, w = d >> 6;
    Pr_s[d] = P[((size_t)b * C_ + c) * C_ + d];
    __syncthreads();
    float a = 0.f;
#pragma unroll 4
    for (int e4 = 0; e4 < 64; ++e4) {
        f32x4 wv = *(const f32x4*)(Wk + (size_t)d * C_ + e4 * 4);
        f32x4 pv = *(const f32x4*)(Pr_s + e4 * 4);
        a += wv.x * pv.x + wv.y * pv.y + wv.z * pv.z + wv.w * pv.w;
    }
    float v = a + (float)N_ * bq[c] * bk[d];
    float m = v;
    for (int off = 32; off; off >>= 1) m = fmaxf(m, __shfl_xor(m, off));
    if (lane == 0) red[w] = m;
    __syncthreads();
    m = fmaxf(fmaxf(red[0], red[1]), fmaxf(red[2], red[3]));
    float e = __expf(v - m);
    float s = e;
    for (int off = 32; off; off >>= 1) s += __shfl_xor(s, off);
    if (lane == 0) red[4 + w] = s;
    __syncthreads();
    s = red[4] + red[5] + red[6] + red[7];
    atten[((size_t)b * C_ + c) * C_ + d] = e / (s * 16.f) + outer[(size_t)c * C_ + d] * 0.0625f;
}

// ------------- A = (atten*Wv + I)*diag(rsig) in FRAGMENT layout, beta ----
__global__ void k_gemm3(const float* __restrict__ atten, const float* __restrict__ Wv,
                        const float* __restrict__ bv, const float* __restrict__ mean,
                        const float* __restrict__ rsig, short* __restrict__ Abf,
                        float* __restrict__ beta) {
    __shared__ float red[4];
    int bid = blockIdx.x; int b = bid >> 8, c = bid & 255; int g = threadIdx.x;
    int lane = g & 63, w = g >> 6;
    const float* at = atten + ((size_t)b * C_ + c) * C_;
    float a = 0.f;
    for (int d = 0; d < C_; ++d)
        a += at[d] * Wv[(size_t)d * C_ + g];
    float Ag = (a + ((g == c) ? 1.f : 0.f)) * rsig[b * C_ + g];
    Abf[(size_t)b * C_ * C_ + ((size_t)(g >> 3) * C_ + c) * 8 + (g & 7)] = f2bf(Ag);
    float u = at[g] * bv[g] - Ag * mean[b * C_ + g];
    for (int off = 32; off; off >>= 1) u += __shfl_xor(u, off);
    if (lane == 0) red[w] = u;
    __syncthreads();
    if (g == 0) beta[b * C_ + c] = red[0] + red[1] + red[2] + red[3];
}

// ------------- Pass 2: out = A*x + beta (R8/R10/R14 known-good) -----------
__global__ __launch_bounds__(512, 4) void k_out2(
        const short* __restrict__ xf, const short* __restrict__ Abf,
        const float* __restrict__ beta, float* __restrict__ out) {
    __shared__ short Xt[2 * 8192];
    __shared__ float Wb[8 * 32 * 33];
    const int t = threadIdx.x, lane = t & 63, wave = t >> 6;
    const int nb = blockIdx.x, b = blockIdx.y;
    const int col = lane & 15, g16 = lane >> 4;
    const int cw0 = wave * 32;
    const int r8 = lane >> 3, s8 = lane & 7;
    const int n_blk = nb * 256;
    const short* Ab = Abf + (size_t)b * C_ * C_;
    const short* xfb = xf + (size_t)b * CN_;
    float* ob = out + (size_t)b * CN_;
    float* wl = Wb + wave * (32 * 33);

    bf16x8 Af[2][8];
#pragma unroll
    for (int ct = 0; ct < 2; ++ct)
#pragma unroll
        for (int ks = 0; ks < 8; ++ks)
            Af[ct][ks] = *(const bf16x8*)(Ab +
                ((size_t)((ks * 4 + g16) * 256 + cw0 + ct * 16 + col)) * 8);
    float bet[4];
#pragma unroll
    for (int j = 0; j < 4; ++j) bet[j] = beta[b * C_ + cw0 + j * 8 + r8];

#define STAGE(BUF, N0)                                                        \
    {                                                                         \
        _Pragma("unroll")                                                     \
        for (int r = 0; r < 2; ++r) {                                         \
            int s = r * 512 + t;                                              \
            int kg = s >> 5, nsl = s & 31;                                    \
            int nn = nsl ^ (kg & 3);                                          \
            gload16s(xfb + ((size_t)kg * N_ + (N0) + nn) * 8,                 \
                     Xt + (BUF) * 8192 + s * 8);                              \
        }                                                                     \
    }

    STAGE(0, n_blk)
    __syncthreads();

    for (int it = 0; it < 8; ++it) {
        const int cur = it & 1;
        if (it + 1 < 8) STAGE(cur ^ 1, n_blk + (it + 1) * 32)
        const int n0 = n_blk + it * 32;

        f32x4 acc[2][2];
#pragma unroll
        for (int i = 0; i < 2; ++i) {
            acc[i][0] = f32x4{0.f, 0.f, 0.f, 0.f};
            acc[i][1] = f32x4{0.f, 0.f, 0.f, 0.f};
        }
#pragma unroll
        for (int ks = 0; ks < 8; ++ks) {
            const int kg = ks * 4 + g16;
            bf16x8 x0 = *(const bf16x8*)(Xt + cur * 8192 +
                                         (kg * 32 + (col ^ (kg & 3))) * 8);
            bf16x8 x1 = *(const bf16x8*)(Xt + cur * 8192 +
                                         (kg * 32 + ((16 + col) ^ (kg & 3))) * 8);
            acc[0][0] = __builtin_amdgcn_mfma_f32_16x16x32_bf16(Af[0][ks], x0, acc[0][0], 0, 0, 0);
            acc[1][0] = __builtin_amdgcn_mfma_f32_16x16x32_bf16(Af[1][ks], x0, acc[1][0], 0, 0, 0);
            acc[0][1] = __builtin_amdgcn_mfma_f32_16x16x32_bf16(Af[0][ks], x1, acc[0][1], 0, 0, 0);
            acc[1][1] = __builtin_amdgcn_mfma_f32_16x16x32_bf16(Af[1][ks], x1, acc[1][1], 0, 0, 0);
        }
#pragma unroll
        for (int ct = 0; ct < 2; ++ct)
#pragma unroll
            for (int nt = 0; nt < 2; ++nt)
#pragma unroll
                for (int rr = 0; rr < 4; ++rr)
                    wl[(ct * 16 + g16 * 4 + rr) * 33 + nt * 16 + col] = acc[ct][nt][rr];
#pragma unroll
        for (int j = 0; j < 4; ++j) {
            f32x4 v = *(const f32x4*)(wl + (j * 8 + r8) * 33 + s8 * 4);
            float bb = bet[j];
            v.x += bb; v.y += bb; v.z += bb; v.w += bb;
            *(f32x4*)(ob + (size_t)(cw0 + j * 8 + r8) * N_ + n0 + s8 * 4) = v;
        }
        __syncthreads();
    }
#undef STAGE
}

// ------------- Pass 2 (fallback, small ws): gathers f32 x ----------------
__global__ __launch_bounds__(512) void k_out_f32(
        const float* __restrict__ x, const short* __restrict__ Abf,
        const float* __restrict__ beta, float* __restrict__ out) {
    __shared__ float beta_s[256];
    const int t = threadIdx.x, lane = t & 63, wave = t >> 6;
    const int nb = blockIdx.x, b = blockIdx.y;
    const int col = lane & 15, g16 = lane >> 4;
    const int n_w = nb * 256 + wave * 32;
    if (t < 256) beta_s[t] = beta[b * C_ + t];
    __syncthreads();
    const short* Ab = Abf + (size_t)b * C_ * C_;
    const float* xb = x + (size_t)b * CN_;
    float* ob = out + (size_t)b * CN_;

    f32x4 acc[16][2];
#pragma unroll
    for (int i = 0; i < 16; ++i) {
        acc[i][0] = f32x4{0.f, 0.f, 0.f, 0.f};
        acc[i][1] = f32x4{0.f, 0.f, 0.f, 0.f};
    }
    float pf[2][16];
#define XL(KS, NT, J) xb[(size_t)((KS)*32 + g16 * 8 + (J)) * N_ + n_w + (NT)*16 + col]
#pragma unroll
    for (int j = 0; j < 8; ++j) { pf[0][j] = XL(0, 0, j); pf[0][8 + j] = XL(0, 1, j); }
#pragma unroll
    for (int ks = 0; ks < 8; ++ks) {
        if (ks + 1 < 8) {
#pragma unroll
            for (int j = 0; j < 8; ++j) {
                pf[(ks + 1) & 1][j] = XL(ks + 1, 0, j);
                pf[(ks + 1) & 1][8 + j] = XL(ks + 1, 1, j);
            }
        }
        bf16x8 xa, xv;
#pragma unroll
        for (int j = 0; j < 8; ++j) {
            xa[j] = f2bf(pf[ks & 1][j]);
            xv[j] = f2bf(pf[ks & 1][8 + j]);
        }
#pragma unroll
        for (int ct = 0; ct < 16; ++ct) {
            bf16x8 afr = *(const bf16x8*)(Ab + ((size_t)((ks * 4 + g16) * 256 + ct * 16 + col)) * 8);
            acc[ct][0] = __builtin_amdgcn_mfma_f32_16x16x32_bf16(afr, xa, acc[ct][0], 0, 0, 0);
            acc[ct][1] = __builtin_amdgcn_mfma_f32_16x16x32_bf16(afr, xv, acc[ct][1], 0, 0, 0);
        }
    }
#undef XL
#pragma unroll
    for (int ct = 0; ct < 16; ++ct)
#pragma unroll
        for (int nt = 0; nt < 2; ++nt) {
            int n = n_w + nt * 16 + col;
#pragma unroll
            for (int rr = 0; rr < 4; ++rr) {
                int c = ct * 16 + g16 * 4 + rr;
                ob[(size_t)c * N_ + n] = acc[ct][nt][rr] + beta_s[c];
            }
        }
}

extern "C" void kernel_launch(void* const* d_in, const int* in_sizes, int n_in,
                              void* d_out, int out_size, void* d_ws, size_t ws_size,
                              hipStream_t stream) {
    (void)in_sizes; (void)n_in; (void)out_size;
    const float* x     = (const float*)d_in[0];
    const float* Wq    = (const float*)d_in[1];
    const float* bq    = (const float*)d_in[2];
    const float* Wk    = (const float*)d_in[3];
    const float* bk    = (const float*)d_in[4];
    const float* Wv    = (const float*)d_in[5];
    const float* bv    = (const float*)d_in[6];
    const float* outer = (const float*)d_in[7];
    float* out = (float*)d_out;

    char* w = (char*)d_ws;
    float* mean   = (float*)(w + 0);
    float* rsig   = (float*)(w + 4096);
    float* beta   = (float*)(w + 8192);
    float* rs2    = (float*)(w + 16384);   // big: 2*256*144*4 = 294912
    float* rspart = (float*)(w + 16384);   // fb : 128*2*256*4 = 262144
    float* Graw   = (float*)(w + 311296);
    float* P      = (float*)(w + 835584);
    float* atten  = (float*)(w + 1359872);
    short* Abf    = (short*)(w + 1884160);
    const size_t fixed = 2146304;
    const size_t part_bytes = (size_t)NCK_ * B_ * C_ * C_ * 4;   // 67.1 MB
    const size_t xf_bytes = (size_t)B_ * CN_ * 2;                // 113.25 MB
    const size_t xg_bytes = (size_t)B_ * CN_ * 2;                // 113.25 MB
    float* part = (float*)(w + fixed);
    short* xf   = (short*)(w + fixed + part_bytes);
    short* xg   = (short*)(w + fixed + part_bytes + xf_bytes);

    const bool big = ws_size >= fixed + part_bytes + xf_bytes + xg_bytes;

    if (big) {
        k_prep   <<<dim3(NB_, 4, B_), 256, 0, stream>>>(x, xg, xf, rs2);
        k_gram_bf<<<dim3(NCK_, B_), 1024, 0, stream>>>(xg, part);
        k_reduce2<<<dim3(B_ * C_), 256, 0, stream>>>(part, rs2, Graw, mean, rsig);
    } else {
        k_gram_fb  <<<dim3(NCK_, B_), 1024, 0, stream>>>(x, part, rspart);
        k_reduce_fb<<<dim3(B_ * C_), 256, 0, stream>>>(part, rspart, Graw, mean, rsig);
    }
    k_gemm1 <<<dim3(B_ * C_), C_, 0, stream>>>(Wq, Graw, mean, rsig, P);
    k_attn  <<<dim3(B_ * C_), C_, 0, stream>>>(P, Wk, bq, bk, outer, atten);
    k_gemm3 <<<dim3(B_ * C_), C_, 0, stream>>>(atten, Wv, bv, mean, rsig, Abf, beta);
    if (big) {
        k_out2  <<<dim3(N_ / 256, B_), 512, 0, stream>>>(xf, Abf, beta, out);
    } else {
        k_out_f32<<<dim3(N_ / 256, B_), 512, 0, stream>>>(x, Abf, beta, out);
    }
}

// Round 16
// 278.172 us; speedup vs baseline: 1.0361x; 1.0056x over previous
//
#include <hip/hip_runtime.h>
#include <hip/hip_bf16.h>

#define B_ 2
#define C_ 256
#define N_ 110592
#define CN_ ((size_t)C_ * N_)
#define NCK_ 128          // K-chunks in gram (grid 256)
#define T_ 27             // 32-col tiles per chunk: 128*27*32 = 110592
#define NB_ 144           // prep n-blocks (768 n each)

typedef __attribute__((ext_vector_type(4))) float f32x4;
typedef __attribute__((ext_vector_type(8))) short bf16x8;
typedef __attribute__((ext_vector_type(4))) short bf16x4;

__device__ __forceinline__ short f2bf(float f) {
    union { float f; unsigned u; } v; v.f = f;
    unsigned r = (v.u + 0x7fffu + ((v.u >> 16) & 1u)) >> 16;
    return (short)(r & 0xffffu);
}

__device__ __forceinline__ void gload16f(const float* g, float* l) {
    __builtin_amdgcn_global_load_lds(
        (const __attribute__((address_space(1))) void*)g,
        (__attribute__((address_space(3))) void*)l, 16, 0, 0);
}

__device__ __forceinline__ void gload16s(const short* g, short* l) {
    __builtin_amdgcn_global_load_lds(
        (const __attribute__((address_space(1))) void*)g,
        (__attribute__((address_space(3))) void*)l, 16, 0, 0);
}

// ---------------- k_prep: x(f32) -> xg + xf + rowsum partials -------------
// R16: xg emit moved behind the barrier and routed through the bf16 LDS
// tile with write-contiguous ordering (per-wave 1-KB dest segments) —
// R15's reg-direct xg write produced 16 scattered 64-B segments per instr.
// Mapping unchanged: xg[tile][c][slot s] holds source granule s^(c&3).
__global__ __launch_bounds__(256) void k_prep(
        const float* __restrict__ x, short* __restrict__ xg,
        short* __restrict__ xf, float* __restrict__ rs2) {
    __shared__ short Xs16[64 * 272];    // 34.8 KB bf16, pitch 272 shorts
    const int t = threadIdx.x;
    const int nb = blockIdx.x, q = blockIdx.y, b = blockIdx.z;
    const int c0 = q * 64, n0 = nb * 768;
    const float* xb = x + (size_t)b * CN_;
    short* xgb = xg + (size_t)b * CN_;
    short* xfb = xf + (size_t)b * CN_;
    const int lg = t >> 5;              // row group 0..7
    const int ln = t & 31;              // n granule (8 floats)
    const int er = t >> 2;              // xg-emit row 0..63
    const int eg = t & 3;               // xg-emit dest slot
    const int egs = eg ^ (er & 3);      // xg-emit source granule
    float racc[8] = {0.f, 0.f, 0.f, 0.f, 0.f, 0.f, 0.f, 0.f};

    for (int sl = 0; sl < 3; ++sl) {
        const int ns = n0 + sl * 256;
        // phase 1: read x -> regs, rowsum, convert, LDS write
#pragma unroll
        for (int i = 0; i < 8; ++i) {
            const int rl = i * 8 + lg;
            const float* src = xb + (size_t)(c0 + rl) * N_ + ns + ln * 8;
            f32x4 v0 = *(const f32x4*)(src);
            f32x4 v1 = *(const f32x4*)(src + 4);
            racc[i] += ((v0.x + v0.y) + (v0.z + v0.w)) +
                       ((v1.x + v1.y) + (v1.z + v1.w));
            bf16x8 h;
            h[0] = f2bf(v0.x); h[1] = f2bf(v0.y); h[2] = f2bf(v0.z); h[3] = f2bf(v0.w);
            h[4] = f2bf(v1.x); h[5] = f2bf(v1.y); h[6] = f2bf(v1.z); h[7] = f2bf(v1.w);
            *(bf16x8*)(Xs16 + rl * 272 + ln * 8) = h;
        }
        __syncthreads();
        // phase 2a: xg emit — per-wave 1-KB contiguous global segments
#pragma unroll
        for (int tau = 0; tau < 8; ++tau) {
            bf16x8 h = *(const bf16x8*)(Xs16 + er * 272 + tau * 32 + egs * 8);
            const int tg = nb * 24 + sl * 8 + tau;
            *(bf16x8*)(xgb + (size_t)tg * 8192 + (c0 + er) * 32 + eg * 8) = h;
        }
        // phase 2b: xf emit (8-ch gather)
#pragma unroll
        for (int nn = 0; nn < 8; ++nn) {
            bf16x8 h;
#pragma unroll
            for (int j = 0; j < 8; ++j)
                h[j] = Xs16[(lg * 8 + j) * 272 + nn * 32 + ln];
            *(bf16x8*)(xfb + ((size_t)(q * 8 + lg) * N_ + ns + nn * 32 + ln) * 8) = h;
        }
        __syncthreads();
    }
    // rowsums: 32 lanes (ln) share row i*8+lg
#pragma unroll
    for (int i = 0; i < 8; ++i) {
        float r = racc[i];
        r += __shfl_xor(r, 1);
        r += __shfl_xor(r, 2);
        r += __shfl_xor(r, 4);
        r += __shfl_xor(r, 8);
        r += __shfl_xor(r, 16);
        if (ln == 0)
            rs2[((size_t)b * C_ + c0 + i * 8 + lg) * NB_ + nb] = r;
    }
}

// ---------------- k_gram_bf: Gram from xg (bf16, swizzled tiles) ----------
// (R14/R15 verbatim — passed.)
__global__ __launch_bounds__(1024, 4) void k_gram_bf(
        const short* __restrict__ xg, float* __restrict__ part) {
    __shared__ short Xs[3 * 8192];      // 3 x 16 KB
    const int t = threadIdx.x, lane = t & 63, wave = t >> 6;
    const int chunk = blockIdx.x, b = blockIdx.y;
    const int cw0 = (wave & 3) * 64, dw0 = (wave >> 2) * 64;
    const int r16 = lane & 15, g16 = lane >> 4;
    const int gsw = g16 ^ (r16 & 3);
    const short* xgb = xg + (size_t)b * CN_ + (size_t)chunk * T_ * 8192;

    f32x4 acc[4][4];
#pragma unroll
    for (int i = 0; i < 4; ++i)
#pragma unroll
        for (int j = 0; j < 4; ++j) acc[i][j] = f32x4{0.f, 0.f, 0.f, 0.f};

#define GST(TT, BB) gload16s(xgb + (size_t)(TT) * 8192 + t * 8, Xs + (BB) * 8192 + t * 8);

    GST(0, 0)
    GST(1, 1)

    int bb = 0;
    for (int tt = 0; tt < T_; ++tt) {
        if (tt + 1 < T_) asm volatile("s_waitcnt vmcnt(1)" ::: "memory");
        else             asm volatile("s_waitcnt vmcnt(0)" ::: "memory");
        __builtin_amdgcn_sched_barrier(0);
        __builtin_amdgcn_s_barrier();
        if (tt + 2 < T_) {
            int bn = bb + 2; if (bn >= 3) bn -= 3;
            GST(tt + 2, bn)
        }
        const short* base = Xs + bb * 8192;
        bf16x8 afr[4];
#pragma unroll
        for (int ct = 0; ct < 4; ++ct)
            afr[ct] = *(const bf16x8*)(base + (cw0 + ct * 16 + r16) * 32 + gsw * 8);
#pragma unroll
        for (int dt = 0; dt < 4; ++dt) {
            bf16x8 bfr = *(const bf16x8*)(base + (dw0 + dt * 16 + r16) * 32 + gsw * 8);
#pragma unroll
            for (int ct = 0; ct < 4; ++ct)
                acc[ct][dt] = __builtin_amdgcn_mfma_f32_16x16x32_bf16(
                    afr[ct], bfr, acc[ct][dt], 0, 0, 0);
        }
        asm volatile("s_waitcnt lgkmcnt(0)" ::: "memory");
        __builtin_amdgcn_sched_barrier(0);
        ++bb; if (bb >= 3) bb -= 3;
    }
#undef GST

    float* pp = part + ((size_t)b * NCK_ + chunk) * (C_ * C_);
#pragma unroll
    for (int ct = 0; ct < 4; ++ct)
#pragma unroll
        for (int dt = 0; dt < 4; ++dt) {
            int d = dw0 + dt * 16 + r16;
#pragma unroll
            for (int rr = 0; rr < 4; ++rr) {
                int c = cw0 + ct * 16 + g16 * 4 + rr;
                pp[(size_t)c * C_ + d] = acc[ct][dt][rr];
            }
        }
}

// ------------- k_reduce2: vectorized reduce + stats (big path) ------------
__global__ void k_reduce2(const float* __restrict__ part, const float* __restrict__ rs2,
                          float* __restrict__ Graw, float* __restrict__ mean,
                          float* __restrict__ rsig) {
    __shared__ f32x4 red[4 * 64];
    __shared__ float rsr[NB_];
    __shared__ float diag_s;
    int bid = blockIdx.x;
    int b = bid >> 8, c = bid & 255;
    int t = threadIdx.x;
    int dq = t & 63, ps = t >> 6;
    f32x4 s = f32x4{0.f, 0.f, 0.f, 0.f};
    for (int p = ps; p < NCK_; p += 4)
        s += *(const f32x4*)(part + (((size_t)b * NCK_ + p) * (C_ * C_)) +
                             (size_t)c * C_ + dq * 4);
    red[ps * 64 + dq] = s;
    if (t < NB_) rsr[t] = rs2[((size_t)b * C_ + c) * NB_ + t];
    __syncthreads();
    if (t < 64) {
        f32x4 a = red[t] + red[64 + t] + red[128 + t] + red[192 + t];
        *(f32x4*)(Graw + ((size_t)b * C_ + c) * C_ + t * 4) = a;
        if (t == (c >> 2)) {
            int m3 = c & 3;
            diag_s = (m3 == 0) ? a.x : ((m3 == 1) ? a.y : ((m3 == 2) ? a.z : a.w));
        }
    }
    __syncthreads();
    if (t == 0) {
        float tot = 0.f;
#pragma unroll
        for (int i = 0; i < NB_; ++i) tot += rsr[i];
        float m = tot / (float)N_;
        float var = diag_s / (float)N_ - m * m;
        mean[b * C_ + c] = m;
        rsig[b * C_ + c] = rsqrtf(var + 1e-5f);
    }
}

// ======== FALLBACK PATH (small ws) — R10 verbatim (proven) ========
__global__ __launch_bounds__(1024, 4) void k_gram_fb(
        const float* __restrict__ x, float* __restrict__ part,
        float* __restrict__ rspart) {
    __shared__ float Xf[3 * 8192];
    __shared__ short Xb[256 * 40];
    __shared__ float rs_s[256];
    const int t = threadIdx.x, lane = t & 63, wave = t >> 6;
    const int chunk = blockIdx.x, b = blockIdx.y;
    const int k0 = chunk * (T_ * 32);
    const int cw0 = (wave & 3) * 64, dw0 = (wave >> 2) * 64;
    const int r16 = lane & 15, g16 = lane >> 4;
    const float* xb = x + (size_t)b * CN_;
    const int s_row = t >> 3;
    const int g_src = (t & 7) ^ (s_row & 7);
    const int rp_r = t >> 2, rp_q = t & 3;
    const int rp_g0 = (2 * rp_q) ^ (rp_r & 7);

    f32x4 acc[4][4];
#pragma unroll
    for (int i = 0; i < 4; ++i)
#pragma unroll
        for (int j = 0; j < 4; ++j) acc[i][j] = f32x4{0.f, 0.f, 0.f, 0.f};
    float rs = 0.f;

#define GSTAGE(TT, BB)                                                        \
    {                                                                         \
        const float* gsrc = xb + k0 + (TT) * 32 + g_src * 4;                  \
        float* ldst = Xf + (BB) * 8192;                                       \
        gload16f(gsrc + (size_t)s_row * N_, ldst + t * 4);                    \
        gload16f(gsrc + (size_t)(s_row + 128) * N_, ldst + (t + 1024) * 4);   \
    }
    GSTAGE(0, 0)
    GSTAGE(1, 1)
    int bb = 0;
    for (int tt = 0; tt < T_; ++tt) {
        if (tt + 1 < T_) asm volatile("s_waitcnt vmcnt(2)" ::: "memory");
        else             asm volatile("s_waitcnt vmcnt(0)" ::: "memory");
        __builtin_amdgcn_s_barrier();
        if (tt + 2 < T_) {
            int bn = bb + 2; if (bn >= 3) bn -= 3;
            GSTAGE(tt + 2, bn)
        }
        {
            const float* src = Xf + bb * 8192 + rp_r * 32;
            f32x4 a = *(const f32x4*)(src + rp_g0 * 4);
            f32x4 c = *(const f32x4*)(src + (rp_g0 ^ 1) * 4);
            rs += ((a.x + a.y) + (a.z + a.w)) + ((c.x + c.y) + (c.z + c.w));
            bf16x8 h;
            h[0] = f2bf(a.x); h[1] = f2bf(a.y); h[2] = f2bf(a.z); h[3] = f2bf(a.w);
            h[4] = f2bf(c.x); h[5] = f2bf(c.y); h[6] = f2bf(c.z); h[7] = f2bf(c.w);
            *(bf16x8*)(Xb + rp_r * 40 + rp_q * 8) = h;
        }
        asm volatile("s_waitcnt lgkmcnt(0)" ::: "memory");
        __builtin_amdgcn_s_barrier();
        {
            bf16x8 afr[4];
#pragma unroll
            for (int ct = 0; ct < 4; ++ct)
                afr[ct] = *(const bf16x8*)(Xb + (cw0 + ct * 16 + r16) * 40 + g16 * 8);
#pragma unroll
            for (int dt = 0; dt < 4; ++dt) {
                bf16x8 bfr = *(const bf16x8*)(Xb + (dw0 + dt * 16 + r16) * 40 + g16 * 8);
#pragma unroll
                for (int ct = 0; ct < 4; ++ct)
                    acc[ct][dt] = __builtin_amdgcn_mfma_f32_16x16x32_bf16(
                        afr[ct], bfr, acc[ct][dt], 0, 0, 0);
            }
        }
        ++bb; if (bb >= 3) bb -= 3;
    }
#undef GSTAGE
    rs += __shfl_xor(rs, 1);
    rs += __shfl_xor(rs, 2);
    if (rp_q == 0) rs_s[rp_r] = rs;
    __syncthreads();
    if (t < 256) rspart[((size_t)b * NCK_ + chunk) * C_ + t] = rs_s[t];
    float* pp = part + ((size_t)b * NCK_ + chunk) * (C_ * C_);
#pragma unroll
    for (int ct = 0; ct < 4; ++ct)
#pragma unroll
        for (int dt = 0; dt < 4; ++dt) {
            int d = dw0 + dt * 16 + r16;
#pragma unroll
            for (int rr = 0; rr < 4; ++rr) {
                int c = cw0 + ct * 16 + g16 * 4 + rr;
                pp[(size_t)c * C_ + d] = acc[ct][dt][rr];
            }
        }
}

__global__ void k_reduce_fb(const float* __restrict__ part, const float* __restrict__ rspart,
                            float* __restrict__ Graw, float* __restrict__ mean,
                            float* __restrict__ rsig) {
    __shared__ float diag_s;
    __shared__ float red[256];
    int bid = blockIdx.x;
    int b = bid >> 8, c = bid & 255;
    int d = threadIdx.x;
    float s = 0.f;
    for (int p = 0; p < NCK_; ++p)
        s += part[(((size_t)b * NCK_ + p) * (C_ * C_)) + (size_t)c * C_ + d];
    Graw[((size_t)b * C_ + c) * C_ + d] = s;
    if (d == c) diag_s = s;
    float rsum = 0.f;
    for (int p = d; p < NCK_; p += 256)
        rsum += rspart[((size_t)b * NCK_ + p) * C_ + c];
    red[d] = rsum;
    __syncthreads();
    if (d < 128) red[d] += red[d + 128];
    __syncthreads();
    if (d < 64) red[d] += red[d + 64];
    __syncthreads();
    if (d == 0) {
        float tot = 0.f;
#pragma unroll
        for (int i = 0; i < 64; ++i) tot += red[i];
        float m = tot / (float)N_;
        float var = diag_s / (float)N_ - m * m;
        mean[b * C_ + c] = m;
        rsig[b * C_ + c] = rsqrtf(var + 1e-5f);
    }
}

// ---------------- P = Wq * Gn ----------------
__global__ void k_gemm1(const float* __restrict__ Wq, const float* __restrict__ Graw,
                        const float* __restrict__ mean, const float* __restrict__ rsig,
                        float* __restrict__ P) {
    int bid = blockIdx.x; int b = bid >> 8, c = bid & 255; int d = threadIdx.x;
    const float* G = Graw + (size_t)b * C_ * C_;
    const float* mb = mean + b * C_;
    const float* rb = rsig + b * C_;
    float md = mb[d], rd = rb[d];
    float a1 = 0.f, a2 = 0.f;
    for (int e = 0; e < C_; ++e) {
        float w = Wq[(size_t)c * C_ + e] * rb[e];
        a1 += w * G[(size_t)e * C_ + d];
        a2 += w * mb[e];
    }
    P[((size_t)b * C_ + c) * C_ + d] = rd * a1 - (float)N_ * md * rd * a2;
}

// ---------------- atten = softmax(P*Wk^T + N bq bk^T)/16 + outer/16 ------
__global__ void k_attn(const float* __restrict__ P, const float* __restrict__ Wk,
                       const float* __restrict__ bq, const float* __restrict__ bk,
                       const float* __restrict__ outer, float* __restrict__ atten) {
    __shared__ float Pr_s[256];
    __shared__ float red[8];
    int bid = blockIdx.x; int b = bid >> 8, c = bid & 255; int d = threadIdx.x;
    int lane = d & 63, w = d >> 6;
    Pr_s[d] = P[((size_t)b * C_ + c) * C_ + d];
    __syncthreads();
    float a = 0.f;
#pragma unroll 4
    for (int e4 = 0; e4 < 64; ++e4) {
        f32x4 wv = *(const f32x4*)(Wk + (size_t)d * C_ + e4 * 4);
        f32x4 pv = *(const f32x4*)(Pr_s + e4 * 4);
        a += wv.x * pv.x + wv.y * pv.y + wv.z * pv.z + wv.w * pv.w;
    }
    float v = a + (float)N_ * bq[c] * bk[d];
    float m = v;
    for (int off = 32; off; off >>= 1) m = fmaxf(m, __shfl_xor(m, off));
    if (lane == 0) red[w] = m;
    __syncthreads();
    m = fmaxf(fmaxf(red[0], red[1]), fmaxf(red[2], red[3]));
    float e = __expf(v - m);
    float s = e;
    for (int off = 32; off; off >>= 1) s += __shfl_xor(s, off);
    if (lane == 0) red[4 + w] = s;
    __syncthreads();
    s = red[4] + red[5] + red[6] + red[7];
    atten[((size_t)b * C_ + c) * C_ + d] = e / (s * 16.f) + outer[(size_t)c * C_ + d] * 0.0625f;
}

// ------------- A = (atten*Wv + I)*diag(rsig) in FRAGMENT layout, beta ----
__global__ void k_gemm3(const float* __restrict__ atten, const float* __restrict__ Wv,
                        const float* __restrict__ bv, const float* __restrict__ mean,
                        const float* __restrict__ rsig, short* __restrict__ Abf,
                        float* __restrict__ beta) {
    __shared__ float red[4];
    int bid = blockIdx.x; int b = bid >> 8, c = bid & 255; int g = threadIdx.x;
    int lane = g & 63, w = g >> 6;
    const float* at = atten + ((size_t)b * C_ + c) * C_;
    float a = 0.f;
    for (int d = 0; d < C_; ++d)
        a += at[d] * Wv[(size_t)d * C_ + g];
    float Ag = (a + ((g == c) ? 1.f : 0.f)) * rsig[b * C_ + g];
    Abf[(size_t)b * C_ * C_ + ((size_t)(g >> 3) * C_ + c) * 8 + (g & 7)] = f2bf(Ag);
    float u = at[g] * bv[g] - Ag * mean[b * C_ + g];
    for (int off = 32; off; off >>= 1) u += __shfl_xor(u, off);
    if (lane == 0) red[w] = u;
    __syncthreads();
    if (g == 0) beta[b * C_ + c] = red[0] + red[1] + red[2] + red[3];
}

// ------------- Pass 2: out = A*x + beta (R8/R10/R14 known-good) -----------
__global__ __launch_bounds__(512, 4) void k_out2(
        const short* __restrict__ xf, const short* __restrict__ Abf,
        const float* __restrict__ beta, float* __restrict__ out) {
    __shared__ short Xt[2 * 8192];
    __shared__ float Wb[8 * 32 * 33];
    const int t = threadIdx.x, lane = t & 63, wave = t >> 6;
    const int nb = blockIdx.x, b = blockIdx.y;
    const int col = lane & 15, g16 = lane >> 4;
    const int cw0 = wave * 32;
    const int r8 = lane >> 3, s8 = lane & 7;
    const int n_blk = nb * 256;
    const short* Ab = Abf + (size_t)b * C_ * C_;
    const short* xfb = xf + (size_t)b * CN_;
    float* ob = out + (size_t)b * CN_;
    float* wl = Wb + wave * (32 * 33);

    bf16x8 Af[2][8];
#pragma unroll
    for (int ct = 0; ct < 2; ++ct)
#pragma unroll
        for (int ks = 0; ks < 8; ++ks)
            Af[ct][ks] = *(const bf16x8*)(Ab +
                ((size_t)((ks * 4 + g16) * 256 + cw0 + ct * 16 + col)) * 8);
    float bet[4];
#pragma unroll
    for (int j = 0; j < 4; ++j) bet[j] = beta[b * C_ + cw0 + j * 8 + r8];

#define STAGE(BUF, N0)                                                        \
    {                                                                         \
        _Pragma("unroll")                                                     \
        for (int r = 0; r < 2; ++r) {                                         \
            int s = r * 512 + t;                                              \
            int kg = s >> 5, nsl = s & 31;                                    \
            int nn = nsl ^ (kg & 3);                                          \
            gload16s(xfb + ((size_t)kg * N_ + (N0) + nn) * 8,                 \
                     Xt + (BUF) * 8192 + s * 8);                              \
        }                                                                     \
    }

    STAGE(0, n_blk)
    __syncthreads();

    for (int it = 0; it < 8; ++it) {
        const int cur = it & 1;
        if (it + 1 < 8) STAGE(cur ^ 1, n_blk + (it + 1) * 32)
        const int n0 = n_blk + it * 32;

        f32x4 acc[2][2];
#pragma unroll
        for (int i = 0; i < 2; ++i) {
            acc[i][0] = f32x4{0.f, 0.f, 0.f, 0.f};
            acc[i][1] = f32x4{0.f, 0.f, 0.f, 0.f};
        }
#pragma unroll
        for (int ks = 0; ks < 8; ++ks) {
            const int kg = ks * 4 + g16;
            bf16x8 x0 = *(const bf16x8*)(Xt + cur * 8192 +
                                         (kg * 32 + (col ^ (kg & 3))) * 8);
            bf16x8 x1 = *(const bf16x8*)(Xt + cur * 8192 +
                                         (kg * 32 + ((16 + col) ^ (kg & 3))) * 8);
            acc[0][0] = __builtin_amdgcn_mfma_f32_16x16x32_bf16(Af[0][ks], x0, acc[0][0], 0, 0, 0);
            acc[1][0] = __builtin_amdgcn_mfma_f32_16x16x32_bf16(Af[1][ks], x0, acc[1][0], 0, 0, 0);
            acc[0][1] = __builtin_amdgcn_mfma_f32_16x16x32_bf16(Af[0][ks], x1, acc[0][1], 0, 0, 0);
            acc[1][1] = __builtin_amdgcn_mfma_f32_16x16x32_bf16(Af[1][ks], x1, acc[1][1], 0, 0, 0);
        }
#pragma unroll
        for (int ct = 0; ct < 2; ++ct)
#pragma unroll
            for (int nt = 0; nt < 2; ++nt)
#pragma unroll
                for (int rr = 0; rr < 4; ++rr)
                    wl[(ct * 16 + g16 * 4 + rr) * 33 + nt * 16 + col] = acc[ct][nt][rr];
#pragma unroll
        for (int j = 0; j < 4; ++j) {
            f32x4 v = *(const f32x4*)(wl + (j * 8 + r8) * 33 + s8 * 4);
            float bb = bet[j];
            v.x += bb; v.y += bb; v.z += bb; v.w += bb;
            *(f32x4*)(ob + (size_t)(cw0 + j * 8 + r8) * N_ + n0 + s8 * 4) = v;
        }
        __syncthreads();
    }
#undef STAGE
}

// ------------- Pass 2 (fallback, small ws): gathers f32 x ----------------
__global__ __launch_bounds__(512) void k_out_f32(
        const float* __restrict__ x, const short* __restrict__ Abf,
        const float* __restrict__ beta, float* __restrict__ out) {
    __shared__ float beta_s[256];
    const int t = threadIdx.x, lane = t & 63, wave = t >> 6;
    const int nb = blockIdx.x, b = blockIdx.y;
    const int col = lane & 15, g16 = lane >> 4;
    const int n_w = nb * 256 + wave * 32;
    if (t < 256) beta_s[t] = beta[b * C_ + t];
    __syncthreads();
    const short* Ab = Abf + (size_t)b * C_ * C_;
    const float* xb = x + (size_t)b * CN_;
    float* ob = out + (size_t)b * CN_;

    f32x4 acc[16][2];
#pragma unroll
    for (int i = 0; i < 16; ++i) {
        acc[i][0] = f32x4{0.f, 0.f, 0.f, 0.f};
        acc[i][1] = f32x4{0.f, 0.f, 0.f, 0.f};
    }
    float pf[2][16];
#define XL(KS, NT, J) xb[(size_t)((KS)*32 + g16 * 8 + (J)) * N_ + n_w + (NT)*16 + col]
#pragma unroll
    for (int j = 0; j < 8; ++j) { pf[0][j] = XL(0, 0, j); pf[0][8 + j] = XL(0, 1, j); }
#pragma unroll
    for (int ks = 0; ks < 8; ++ks) {
        if (ks + 1 < 8) {
#pragma unroll
            for (int j = 0; j < 8; ++j) {
                pf[(ks + 1) & 1][j] = XL(ks + 1, 0, j);
                pf[(ks + 1) & 1][8 + j] = XL(ks + 1, 1, j);
            }
        }
        bf16x8 xa, xv;
#pragma unroll
        for (int j = 0; j < 8; ++j) {
            xa[j] = f2bf(pf[ks & 1][j]);
            xv[j] = f2bf(pf[ks & 1][8 + j]);
        }
#pragma unroll
        for (int ct = 0; ct < 16; ++ct) {
            bf16x8 afr = *(const bf16x8*)(Ab + ((size_t)((ks * 4 + g16) * 256 + ct * 16 + col)) * 8);
            acc[ct][0] = __builtin_amdgcn_mfma_f32_16x16x32_bf16(afr, xa, acc[ct][0], 0, 0, 0);
            acc[ct][1] = __builtin_amdgcn_mfma_f32_16x16x32_bf16(afr, xv, acc[ct][1], 0, 0, 0);
        }
    }
#undef XL
#pragma unroll
    for (int ct = 0; ct < 16; ++ct)
#pragma unroll
        for (int nt = 0; nt < 2; ++nt) {
            int n = n_w + nt * 16 + col;
#pragma unroll
            for (int rr = 0; rr < 4; ++rr) {
                int c = ct * 16 + g16 * 4 + rr;
                ob[(size_t)c * N_ + n] = acc[ct][nt][rr] + beta_s[c];
            }
        }
}

extern "C" void kernel_launch(void* const* d_in, const int* in_sizes, int n_in,
                              void* d_out, int out_size, void* d_ws, size_t ws_size,
                              hipStream_t stream) {
    (void)in_sizes; (void)n_in; (void)out_size;
    const float* x     = (const float*)d_in[0];
    const float* Wq    = (const float*)d_in[1];
    const float* bq    = (const float*)d_in[2];
    const float* Wk    = (const float*)d_in[3];
    const float* bk    = (const float*)d_in[4];
    const float* Wv    = (const float*)d_in[5];
    const float* bv    = (const float*)d_in[6];
    const float* outer = (const float*)d_in[7];
    float* out = (float*)d_out;

    char* w = (char*)d_ws;
    float* mean   = (float*)(w + 0);
    float* rsig   = (float*)(w + 4096);
    float* beta   = (float*)(w + 8192);
    float* rs2    = (float*)(w + 16384);   // big: 2*256*144*4 = 294912
    float* rspart = (float*)(w + 16384);   // fb : 128*2*256*4 = 262144
    float* Graw   = (float*)(w + 311296);
    float* P      = (float*)(w + 835584);
    float* atten  = (float*)(w + 1359872);
    short* Abf    = (short*)(w + 1884160);
    const size_t fixed = 2146304;
    const size_t part_bytes = (size_t)NCK_ * B_ * C_ * C_ * 4;   // 67.1 MB
    const size_t xf_bytes = (size_t)B_ * CN_ * 2;                // 113.25 MB
    const size_t xg_bytes = (size_t)B_ * CN_ * 2;                // 113.25 MB
    float* part = (float*)(w + fixed);
    short* xf   = (short*)(w + fixed + part_bytes);
    short* xg   = (short*)(w + fixed + part_bytes + xf_bytes);

    const bool big = ws_size >= fixed + part_bytes + xf_bytes + xg_bytes;

    if (big) {
        k_prep   <<<dim3(NB_, 4, B_), 256, 0, stream>>>(x, xg, xf, rs2);
        k_gram_bf<<<dim3(NCK_, B_), 1024, 0, stream>>>(xg, part);
        k_reduce2<<<dim3(B_ * C_), 256, 0, stream>>>(part, rs2, Graw, mean, rsig);
    } else {
        k_gram_fb  <<<dim3(NCK_, B_), 1024, 0, stream>>>(x, part, rspart);
        k_reduce_fb<<<dim3(B_ * C_), 256, 0, stream>>>(part, rspart, Graw, mean, rsig);
    }
    k_gemm1 <<<dim3(B_ * C_), C_, 0, stream>>>(Wq, Graw, mean, rsig, P);
    k_attn  <<<dim3(B_ * C_), C_, 0, stream>>>(P, Wk, bq, bk, outer, atten);
    k_gemm3 <<<dim3(B_ * C_), C_, 0, stream>>>(atten, Wv, bv, mean, rsig, Abf, beta);
    if (big) {
        k_out2  <<<dim3(N_ / 256, B_), 512, 0, stream>>>(xf, Abf, beta, out);
    } else {
        k_out_f32<<<dim3(N_ / 256, B_), 512, 0, stream>>>(x, Abf, beta, out);
    }
}